// Round 15
// baseline (2103.848 us; speedup 1.0000x reference)
//
#include <hip/hip_runtime.h>
#include <hip/hip_bf16.h>
#include <math.h>

typedef unsigned int u32;
typedef unsigned short u16;
typedef __attribute__((ext_vector_type(8))) short bf16x8;
typedef __attribute__((ext_vector_type(4))) float f32x4;

#define NBATCH 1024
#define TT 128
#define NB 8          // rows per block (was 16) -> half-size blocks
#define NBLK 128      // 2 blocks per CU
#define OUTD 32

// ---- ws fragment offsets (u16 indices); gW3 stored with permuted cols n*64+l ----
#define F_DW1 0
#define F_GW1 8192
#define F_DW2 16384
#define F_GW2 32768
#define F_DW3 49152
#define F_GW3 57344
#define F_RO1 188416
#define F_RO2 196608
#define U16_END 200704
#define FW_EMB 0
#define FW_W0D 4096
#define FW_W0G 4224

// ---- LDS map: u16 plane offsets (rows 8-15 kept but zeroed; layout identical to r8/r12) ----
#define ZHI   0        // [16][72]
#define ZLO   1152
#define H1HI  2304     // [2][16][136]
#define H1LO  6656
#define H2HI  11008
#define H2LO  15360
#define YBHI  19712    // [16][72]
#define YBLO  20864
#define HROHI 22016    // [16][136]
#define HROLO 24192
// ---- f32 offsets (FB3G removed -> 81152 B total, 2 blocks/CU) ----
#define FUP   13184    // [2][16][68]
#define FVP   15360
#define FF1   17536    // [16][68]
#define FDW   18624    // [16][16][2]  (dwi, dwn) pairs
#define FW0D  19168
#define FW0G  19296
#define FB1D  19424
#define FB1G  19552
#define FB2D  19680
#define FB2G  19808
#define FB3D  19936    // [64]
#define FRB1  20000    // [128]
#define FRB2  20128    // [32]
#define FTS   20160    // [128]
#define LDS_FLOATS 20288   // 81152 bytes

__device__ __forceinline__ float lipswish(float x) {
  return 0.909f * x / (1.0f + expf(-x));
}
__device__ __forceinline__ u32 bf16r(float x) {
  u32 u = __float_as_uint(x);
  return ((u + 0x7fffu + ((u >> 16) & 1u)) >> 16) & 0xffffu;
}
__device__ __forceinline__ void splitw(float x, u16& h, u16& l) {
  const u32 hb = bf16r(x);
  h = (u16)hb;
  l = (u16)bf16r(x - __uint_as_float(hb << 16));
}

// ---------------- prep: weight-norm + bf16 fragment pack (verbatim r12, verified) ----------------
__global__ void prep_kernel(const float* dr_v1, const float* dr_g1,
                            const float* dr_v2, const float* dr_g2,
                            const float* dr_v3, const float* dr_g3,
                            const float* di_v1, const float* di_g1,
                            const float* di_v2, const float* di_g2,
                            const float* di_v3, const float* di_g3,
                            const float* emb_W, const float* ro_W1, const float* ro_W2,
                            float* ws) {
  __shared__ float sred[2];
  u16* wsu = (u16*)ws;
  float* wsf = (float*)(wsu + U16_END);
  const int mat = blockIdx.y;
  const int row = blockIdx.x;
  const int i = threadIdx.x;
  const float* v = nullptr; const float* g = nullptr;
  int rows = 0, len = 0, O = 0; long F = -1; int l1 = 0; int w0 = 0;
  switch (mat) {
    case 0: v = dr_v1; g = dr_g1; rows = 128;  len = 65;  O = 128;  F = F_DW1; l1 = 1; w0 = FW_W0D; break;
    case 1: v = dr_v2; g = dr_g2; rows = 128;  len = 128; O = 128;  F = F_DW2; break;
    case 2: v = dr_v3; g = dr_g3; rows = 64;   len = 128; O = 64;   F = F_DW3; break;
    case 3: v = di_v1; g = di_g1; rows = 128;  len = 65;  O = 128;  F = F_GW1; l1 = 1; w0 = FW_W0G; break;
    case 4: v = di_v2; g = di_g2; rows = 128;  len = 128; O = 128;  F = F_GW2; break;
    case 5: v = di_v3; g = di_g3; rows = 1024; len = 128; O = 1024; F = F_GW3; break;
    case 6: v = emb_W; g = nullptr; rows = 64;  len = 64;  break;
    case 7: v = ro_W1; g = nullptr; rows = 128; len = 64;  O = 128; F = F_RO1; break;
    case 8: v = ro_W2; g = nullptr; rows = 32;  len = 128; O = 32;  F = F_RO2; break;
  }
  if (row >= rows) return;
  const float x = (i < len) ? v[(size_t)row * len + i] : 0.0f;
  float scale = 1.0f;
  if (g != nullptr) {
    float ss = x * x;
    #pragma unroll
    for (int d = 1; d < 64; d <<= 1) ss += __shfl_xor(ss, d);
    if ((i & 63) == 0) sred[i >> 6] = ss;
    __syncthreads();
    scale = g[row] / sqrtf(sred[0] + sred[1]);
  }
  const float xs = x * scale;
  if (mat == 6) {
    if (i < len) wsf[FW_EMB + i * 64 + row] = xs;
    return;
  }
  int ro = row;
  if (mat == 5) ro = ((row & 15) << 6) | (row >> 4);   // col permute: n*64 + l
  if (l1) {
    if (i == 0) wsf[w0 + row] = xs;
    if (i >= 1 && i < len) {
      const int kk = i - 1;
      wsu[F + ((size_t)((kk >> 3) * O + ro)) * 8 + (kk & 7)] = (u16)bf16r(xs);
    }
  } else if (i < len) {
    wsu[F + ((size_t)((i >> 3) * O + ro)) * 8 + (i & 7)] = (u16)bf16r(xs);
  }
}

__device__ __forceinline__ f32x4 mfma2(bf16x8 hi, bf16x8 lo, bf16x8 b, f32x4 acc) {
  acc = __builtin_amdgcn_mfma_f32_16x16x32_bf16(hi, b, acc, 0, 0, 0);
  acc = __builtin_amdgcn_mfma_f32_16x16x32_bf16(lo, b, acc, 0, 0, 0);
  return acc;
}
__device__ __forceinline__ bf16x8 ldfrag(const u16* p) { return *(const bf16x8*)p; }

#define PIN(x) asm volatile("" : "+v"(x))
#define PIN4(a) { PIN(a[0]); PIN(a[1]); PIN(a[2]); PIN(a[3]); }

// ---------------- main persistent kernel: 128 blocks x 512 threads, 8 rows/block ----------------
__global__ void __launch_bounds__(512)
sde_main(const float* __restrict__ init_noise, const float* __restrict__ bm,
         const float* __restrict__ ts_g, const int* __restrict__ p_steps,
         const int* __restrict__ p_mult, const float* __restrict__ emb_b,
         const float* __restrict__ dr_b1, const float* __restrict__ dr_b2, const float* __restrict__ dr_b3,
         const float* __restrict__ di_b1, const float* __restrict__ di_b2, const float* __restrict__ di_b3,
         const float* __restrict__ ro_b1, const float* __restrict__ ro_b2,
         const float* __restrict__ ws, float* __restrict__ out)
{
  __shared__ __align__(16) float sm[LDS_FLOATS];   // 81152 B -> 2 blocks/CU
  u16* lu = (u16*)sm;

  const int t = threadIdx.x;
  const int b0 = blockIdx.x * NB;
  const u16* __restrict__ wsu = (const u16*)ws;
  const float* __restrict__ wsf = (const float*)(wsu + U16_END);
  const int steps = p_steps[0], mult = p_mult[0];

  // ---- stage constants ----
  {
    if (t < 128) { sm[FTS + t] = ts_g[t]; sm[FW0D + t] = wsf[FW_W0D + t]; sm[FW0G + t] = wsf[FW_W0G + t]; }
    else if (t < 256) { const int i = t - 128; sm[FB1D + i] = dr_b1[i]; sm[FB1G + i] = di_b1[i]; }
    else if (t < 384) { const int i = t - 256; sm[FB2D + i] = dr_b2[i]; sm[FB2G + i] = di_b2[i]; }
    else { const int i = t - 384; sm[FRB1 + i] = ro_b1[i];
           if (i < 64) sm[FB3D + i] = dr_b3[i];
           else if (i < 96) sm[FRB2 + i - 64] = ro_b2[i - 64]; }
    if (t < 256) { float2 zz; zz.x = 0.f; zz.y = 0.f;      // zeroes ALL 16 FDW rows; rows 8-15 stay 0
                   *(float2*)&sm[FDW + (t >> 4) * 32 + (t & 15) * 2] = zz; }
  }

  // ---- init: y0 = init_noise @ embT + emb_b for rows < NB; rows 8-15 zeroed ----
  const int r_own = t >> 5;
  const int o_own = (t & 31) * 2;
  float yA = 0.f, yB = 0.f, zA = 0.f, zB = 0.f, fA = 0.f, fB = 0.f, vA = 0.f, vB = 0.f;
  {
    float a0 = 0.f, a1 = 0.f;
    if (r_own < NB) {
      const float* __restrict__ inr = init_noise + (size_t)(b0 + r_own) * 64;
      a0 = emb_b[o_own]; a1 = emb_b[o_own + 1];
      #pragma unroll 8
      for (int i = 0; i < 64; ++i) {
        const float x = inr[i];
        a0 = fmaf(x, wsf[FW_EMB + i * 64 + o_own], a0);
        a1 = fmaf(x, wsf[FW_EMB + i * 64 + o_own + 1], a1);
      }
    }
    yA = a0; zA = a0; yB = a1; zB = a1;
    u16 h0, l0, h1, l1;
    splitw(a0, h0, l0); splitw(a1, h1, l1);
    const u32 hw = (u32)h0 | ((u32)h1 << 16);
    const u32 lw = (u32)l0 | ((u32)l1 << 16);
    *(u32*)(lu + ZHI + r_own * 72 + o_own) = hw;
    *(u32*)(lu + ZLO + r_own * 72 + o_own) = lw;
    *(u32*)(lu + YBHI + r_own * 72 + o_own) = hw;
    *(u32*)(lu + YBLO + r_own * 72 + o_own) = lw;
  }

  const int w = t >> 6;          // wave 0..7
  const int lane = t & 63;
  const int g = lane >> 4;       // k-octet group
  const int c = lane & 15;       // A-row / col index
  const int net = w >> 2;        // waves 0-3 drift, 4-7 diffusion
  const int nt0 = (w & 3) * 2;   // two N-tiles per wave (L1/L2)
  const int lt = w & 3;          // gW3 latent tile
  const int nh = w >> 2;         // gW3 noise half

  // ---- resident weight fragments ----
  bf16x8 rg3[8][4];
  #pragma unroll
  for (int a = 0; a < 8; ++a) {
    const int colb = (nh * 8 + a) * 64 + lt * 16 + c;
    #pragma unroll
    for (int kt = 0; kt < 4; ++kt)
      rg3[a][kt] = ldfrag(wsu + F_GW3 + ((size_t)((kt * 4 + g) * 1024 + colb)) * 8);
  }
  bf16x8 rw1[2][2], rw2[2][4];
  #pragma unroll
  for (int ti = 0; ti < 2; ++ti) {
    const int col = (nt0 + ti) * 16 + c;
    #pragma unroll
    for (int kt = 0; kt < 2; ++kt)
      rw1[ti][kt] = ldfrag(wsu + (net ? F_GW1 : F_DW1) + ((size_t)((kt * 4 + g) * 128 + col)) * 8);
    #pragma unroll
    for (int kt = 0; kt < 4; ++kt)
      rw2[ti][kt] = ldfrag(wsu + (net ? F_GW2 : F_DW2) + ((size_t)((kt * 4 + g) * 128 + col)) * 8);
  }
  bf16x8 rro1[2];
  #pragma unroll
  for (int kt = 0; kt < 2; ++kt)
    rro1[kt] = ldfrag(wsu + F_RO1 + ((size_t)((kt * 4 + g) * 128 + w * 16 + c)) * 8);
  bf16x8 rx4[4];                 // dW3 tile (waves 0-3) or ro2 tile (waves 6-7)
  {
    const long base = (w < 4) ? (long)F_DW3 : (long)F_RO2;
    const int O3 = (w < 4) ? 64 : 32;
    const int col3 = ((w < 4) ? w : ((w >= 6) ? (w - 6) : 0)) * 16 + c;
    #pragma unroll
    for (int kt = 0; kt < 4; ++kt)
      rx4[kt] = ldfrag(wsu + base + ((size_t)((kt * 4 + g) * O3 + col3)) * 8);
  }
  // gW3 bias for this wave's (nh, lt) block -> registers (replaces LDS FB3G)
  float cb3[8];
  #pragma unroll
  for (int a = 0; a < 8; ++a)
    cb3[a] = di_b3[(lt * 16 + c) * 16 + (nh * 8 + a)];

  __syncthreads();

  #pragma unroll 1
  for (int k = 0; k < TT; ++k) {
    // loop-carried pins: batch-issue resident-fragment reloads at loop top
    #pragma unroll
    for (int a = 0; a < 8; ++a) PIN4(rg3[a]);
    PIN(rw1[0][0]); PIN(rw1[0][1]); PIN(rw1[1][0]); PIN(rw1[1][1]);
    PIN4(rw2[0]); PIN4(rw2[1]);
    PIN(rro1[0]); PIN(rro1[1]);
    PIN4(rx4);

    const float tval = sm[FTS + k];

    // ==== P1: L1 both nets + ro1(y[k-1]) + noise rotation (rows<8 only) ====
    {
      bf16x8 zh[2], zl[2];
      #pragma unroll
      for (int kt = 0; kt < 2; ++kt) {
        zh[kt] = ldfrag(lu + ZHI + c * 72 + kt * 32 + g * 8);
        zl[kt] = ldfrag(lu + ZLO + c * 72 + kt * 32 + g * 8);
      }
      #pragma unroll
      for (int ti = 0; ti < 2; ++ti) {
        const int col = (nt0 + ti) * 16 + c;
        const float ci = net ? fmaf(tval, sm[FW0G + col], sm[FB1G + col])
                             : fmaf(tval, sm[FW0D + col], sm[FB1D + col]);
        f32x4 acc = {ci, ci, ci, ci};
        #pragma unroll
        for (int kt = 0; kt < 2; ++kt) acc = mfma2(zh[kt], zl[kt], rw1[ti][kt], acc);
        #pragma unroll
        for (int j = 0; j < 4; ++j) {
          u16 hh, ll; splitw(lipswish(acc[j]), hh, ll);
          lu[H1HI + net * 2176 + (g * 4 + j) * 136 + col] = hh;
          lu[H1LO + net * 2176 + (g * 4 + j) * 136 + col] = ll;
        }
      }
      if (k > 0) {           // readout stage 1 for token k-1
        bf16x8 yh[2], yl[2];
        #pragma unroll
        for (int kt = 0; kt < 2; ++kt) {
          yh[kt] = ldfrag(lu + YBHI + c * 72 + kt * 32 + g * 8);
          yl[kt] = ldfrag(lu + YBLO + c * 72 + kt * 32 + g * 8);
        }
        const int col = w * 16 + c;
        const float ci = sm[FRB1 + col];
        f32x4 acc = {ci, ci, ci, ci};
        #pragma unroll
        for (int kt = 0; kt < 2; ++kt) acc = mfma2(yh[kt], yl[kt], rro1[kt], acc);
        #pragma unroll
        for (int j = 0; j < 4; ++j) {
          u16 hh, ll; splitw(lipswish(acc[j]), hh, ll);
          lu[HROHI + (g * 4 + j) * 136 + col] = hh;
          lu[HROLO + (g * 4 + j) * 136 + col] = ll;
        }
      }
      if (t >= 256 && t < 384) {   // rotate noise for rows 0-7 only
        const int i2 = t - 256, rr = i2 >> 4, nn = i2 & 15;
        const float old = sm[FDW + rr * 32 + nn * 2 + 1];
        float nv = 0.f;
        if (k < TT - 1)
          nv = bm[((size_t)k * NBATCH + b0 + rr) * 16 + nn] * sqrtf(sm[FTS + k + 1] - tval);
        float2 wv; wv.x = old; wv.y = nv;
        *(float2*)&sm[FDW + rr * 32 + nn * 2] = wv;
      }
    }
    __syncthreads();

    // ==== P2: L2 both nets + ro2 -> out token k-1 (rows<8 stores) ====
    {
      bf16x8 ah[4], al[4];
      #pragma unroll
      for (int kt = 0; kt < 4; ++kt) {
        ah[kt] = ldfrag(lu + H1HI + net * 2176 + c * 136 + kt * 32 + g * 8);
        al[kt] = ldfrag(lu + H1LO + net * 2176 + c * 136 + kt * 32 + g * 8);
      }
      #pragma unroll
      for (int ti = 0; ti < 2; ++ti) {
        const int col = (nt0 + ti) * 16 + c;
        const float ci = net ? sm[FB2G + col] : sm[FB2D + col];
        f32x4 acc = {ci, ci, ci, ci};
        #pragma unroll
        for (int kt = 0; kt < 4; ++kt) acc = mfma2(ah[kt], al[kt], rw2[ti][kt], acc);
        #pragma unroll
        for (int j = 0; j < 4; ++j) {
          u16 hh, ll; splitw(lipswish(acc[j]), hh, ll);
          lu[H2HI + net * 2176 + (g * 4 + j) * 136 + col] = hh;
          lu[H2LO + net * 2176 + (g * 4 + j) * 136 + col] = ll;
        }
      }
      if (k > 0 && w >= 6) { // readout stage 2, token k-1
        bf16x8 hh[4], hl[4];
        #pragma unroll
        for (int kt = 0; kt < 4; ++kt) {
          hh[kt] = ldfrag(lu + HROHI + c * 136 + kt * 32 + g * 8);
          hl[kt] = ldfrag(lu + HROLO + c * 136 + kt * 32 + g * 8);
        }
        const int col = (w - 6) * 16 + c;
        const float ci = sm[FRB2 + col];
        f32x4 acc = {ci, ci, ci, ci};
        #pragma unroll
        for (int kt = 0; kt < 4; ++kt) acc = mfma2(hh[kt], hl[kt], rx4[kt], acc);
        const int tg = k - 1;
        const int matched = (mult > 0 && (tg % mult) == 0) ? (tg / mult) : -1;
        if (g < 2) {
          #pragma unroll
          for (int j = 0; j < 4; ++j) {
            const int m = g * 4 + j;
            out[((size_t)(b0 + m) * TT + tg) * OUTD + col] = acc[j];
            if (matched >= 0 && matched < steps)
              out[(size_t)NBATCH * TT * OUTD + ((size_t)(b0 + m) * steps + matched) * OUTD + col] = acc[j];
          }
        }
      }
    }
    __syncthreads();

    // ==== P3: dW3 (waves 0-3) + gW3 (resident) with in-flight contraction ====
    {
      if (w < 4) {
        bf16x8 dh[4], dl[4];
        #pragma unroll
        for (int kt = 0; kt < 4; ++kt) {
          dh[kt] = ldfrag(lu + H2HI + c * 136 + kt * 32 + g * 8);
          dl[kt] = ldfrag(lu + H2LO + c * 136 + kt * 32 + g * 8);
        }
        const int col = w * 16 + c;
        const float ci = sm[FB3D + col];
        f32x4 acc = {ci, ci, ci, ci};
        #pragma unroll
        for (int kt = 0; kt < 4; ++kt) acc = mfma2(dh[kt], dl[kt], rx4[kt], acc);
        #pragma unroll
        for (int j = 0; j < 4; ++j) sm[FF1 + (g * 4 + j) * 68 + col] = acc[j];
      }
      bf16x8 gh[4], gl[4];
      #pragma unroll
      for (int kt = 0; kt < 4; ++kt) {
        gh[kt] = ldfrag(lu + H2HI + 2176 + c * 136 + kt * 32 + g * 8);
        gl[kt] = ldfrag(lu + H2LO + 2176 + c * 136 + kt * 32 + g * 8);
      }
      float ua[4] = {0.f, 0.f, 0.f, 0.f}, va[4] = {0.f, 0.f, 0.f, 0.f};
      #pragma unroll
      for (int a = 0; a < 8; ++a) {
        const int n = nh * 8 + a;
        const float ci = cb3[a];
        f32x4 acc = {ci, ci, ci, ci};
        #pragma unroll
        for (int kt = 0; kt < 4; ++kt) acc = mfma2(gh[kt], gl[kt], rg3[a][kt], acc);
        #pragma unroll
        for (int j = 0; j < 4; ++j) {
          const float2 dw = *(const float2*)&sm[FDW + (g * 4 + j) * 32 + n * 2];
          ua[j] = fmaf(acc[j], dw.x, ua[j]);
          va[j] = fmaf(acc[j], dw.y, va[j]);
        }
      }
      #pragma unroll
      for (int j = 0; j < 4; ++j) {
        sm[FUP + nh * 1088 + (g * 4 + j) * 68 + lt * 16 + c] = ua[j];
        sm[FVP + nh * 1088 + (g * 4 + j) * 68 + lt * 16 + c] = va[j];
      }
    }
    __syncthreads();

    // ==== P4: Heun update (owner regs) + state planes ====
    {
      const float2 f1v = *(const float2*)&sm[FF1 + r_own * 68 + o_own];
      const float2 u0 = *(const float2*)&sm[FUP + r_own * 68 + o_own];
      const float2 u1p = *(const float2*)&sm[FUP + 1088 + r_own * 68 + o_own];
      const float2 v0 = *(const float2*)&sm[FVP + r_own * 68 + o_own];
      const float2 v1p = *(const float2*)&sm[FVP + 1088 + r_own * 68 + o_own];
      const float u1A = u0.x + u1p.x, u1B = u0.y + u1p.y;
      const float v1A = v0.x + v1p.x, v1B = v0.y + v1p.y;
      const float dti = (k > 0) ? (tval - sm[FTS + k - 1]) : 0.f;
      const float dtn = (k < TT - 1) ? (sm[FTS + k + 1] - tval) : 0.f;
      yA += 0.5f * (fA + f1v.x) * dti + 0.5f * (vA + u1A);
      yB += 0.5f * (fB + f1v.y) * dti + 0.5f * (vB + u1B);
      zA = 2.f * yA - zA + f1v.x * dtn + v1A;
      zB = 2.f * yB - zB + f1v.y * dtn + v1B;
      fA = f1v.x; fB = f1v.y; vA = v1A; vB = v1B;
      u16 h0, l0, h1, l1;
      splitw(zA, h0, l0); splitw(zB, h1, l1);
      *(u32*)(lu + ZHI + r_own * 72 + o_own) = (u32)h0 | ((u32)h1 << 16);
      *(u32*)(lu + ZLO + r_own * 72 + o_own) = (u32)l0 | ((u32)l1 << 16);
      splitw(yA, h0, l0); splitw(yB, h1, l1);
      *(u32*)(lu + YBHI + r_own * 72 + o_own) = (u32)h0 | ((u32)h1 << 16);
      *(u32*)(lu + YBLO + r_own * 72 + o_own) = (u32)l0 | ((u32)l1 << 16);
    }
    __syncthreads();
  }

  // ==== tail: readout of token TT-1 ====
  {
    bf16x8 yh[2], yl[2];
    #pragma unroll
    for (int kt = 0; kt < 2; ++kt) {
      yh[kt] = ldfrag(lu + YBHI + c * 72 + kt * 32 + g * 8);
      yl[kt] = ldfrag(lu + YBLO + c * 72 + kt * 32 + g * 8);
    }
    const int col = w * 16 + c;
    const float ci = sm[FRB1 + col];
    f32x4 acc = {ci, ci, ci, ci};
    #pragma unroll
    for (int kt = 0; kt < 2; ++kt) acc = mfma2(yh[kt], yl[kt], rro1[kt], acc);
    #pragma unroll
    for (int j = 0; j < 4; ++j) {
      u16 hh, ll; splitw(lipswish(acc[j]), hh, ll);
      lu[HROHI + (g * 4 + j) * 136 + col] = hh;
      lu[HROLO + (g * 4 + j) * 136 + col] = ll;
    }
  }
  __syncthreads();
  if (w >= 6) {
    bf16x8 hh[4], hl[4];
    #pragma unroll
    for (int kt = 0; kt < 4; ++kt) {
      hh[kt] = ldfrag(lu + HROHI + c * 136 + kt * 32 + g * 8);
      hl[kt] = ldfrag(lu + HROLO + c * 136 + kt * 32 + g * 8);
    }
    const int col = (w - 6) * 16 + c;
    const float ci = sm[FRB2 + col];
    f32x4 acc = {ci, ci, ci, ci};
    #pragma unroll
    for (int kt = 0; kt < 4; ++kt) acc = mfma2(hh[kt], hl[kt], rx4[kt], acc);
    const int tg = TT - 1;
    const int matched = (mult > 0 && (tg % mult) == 0) ? (tg / mult) : -1;
    if (g < 2) {
      #pragma unroll
      for (int j = 0; j < 4; ++j) {
        const int m = g * 4 + j;
        out[((size_t)(b0 + m) * TT + tg) * OUTD + col] = acc[j];
        if (matched >= 0 && matched < steps)
          out[(size_t)NBATCH * TT * OUTD + ((size_t)(b0 + m) * steps + matched) * OUTD + col] = acc[j];
      }
    }
  }
}

extern "C" void kernel_launch(void* const* d_in, const int* in_sizes, int n_in,
                              void* d_out, int out_size, void* d_ws, size_t ws_size,
                              hipStream_t stream) {
  (void)in_sizes; (void)n_in; (void)out_size; (void)ws_size;
  const float* init_noise = (const float*)d_in[0];
  const float* bm_noise   = (const float*)d_in[1];
  const float* ts         = (const float*)d_in[2];
  const int*   p_steps    = (const int*)d_in[3];
  const int*   p_mult     = (const int*)d_in[4];
  const float* emb_W = (const float*)d_in[5];
  const float* emb_b = (const float*)d_in[6];
  const float* dr_v1 = (const float*)d_in[7];
  const float* dr_g1 = (const float*)d_in[8];
  const float* dr_b1 = (const float*)d_in[9];
  const float* dr_v2 = (const float*)d_in[10];
  const float* dr_g2 = (const float*)d_in[11];
  const float* dr_b2 = (const float*)d_in[12];
  const float* dr_v3 = (const float*)d_in[13];
  const float* dr_g3 = (const float*)d_in[14];
  const float* dr_b3 = (const float*)d_in[15];
  const float* di_v1 = (const float*)d_in[16];
  const float* di_g1 = (const float*)d_in[17];
  const float* di_b1 = (const float*)d_in[18];
  const float* di_v2 = (const float*)d_in[19];
  const float* di_g2 = (const float*)d_in[20];
  const float* di_b2 = (const float*)d_in[21];
  const float* di_v3 = (const float*)d_in[22];
  const float* di_g3 = (const float*)d_in[23];
  const float* di_b3 = (const float*)d_in[24];
  const float* ro_W1 = (const float*)d_in[25];
  const float* ro_b1 = (const float*)d_in[26];
  const float* ro_W2 = (const float*)d_in[27];
  const float* ro_b2 = (const float*)d_in[28];
  float* ws = (float*)d_ws;
  float* out = (float*)d_out;

  prep_kernel<<<dim3(1024, 9), 128, 0, stream>>>(
      dr_v1, dr_g1, dr_v2, dr_g2, dr_v3, dr_g3,
      di_v1, di_g1, di_v2, di_g2, di_v3, di_g3,
      emb_W, ro_W1, ro_W2, ws);

  sde_main<<<NBLK, 512, 0, stream>>>(
      init_noise, bm_noise, ts, p_steps, p_mult,
      emb_b, dr_b1, dr_b2, dr_b3, di_b1, di_b2, di_b3,
      ro_b1, ro_b2, ws, out);
}

// Round 16
// 1241.836 us; speedup vs baseline: 1.6941x; 1.6941x over previous
//
#include <hip/hip_runtime.h>
#include <hip/hip_bf16.h>
#include <math.h>

typedef unsigned int u32;
typedef unsigned short u16;
typedef __attribute__((ext_vector_type(8))) short bf16x8;
typedef __attribute__((ext_vector_type(4))) float f32x4;

#define NBATCH 1024
#define TT 128
#define NB 8          // rows per block -> half-size blocks, 2 blocks/CU
#define NBLK 128
#define OUTD 32

// ---- ws fragment offsets (u16 indices); gW3 stored with permuted cols n*64+l ----
#define F_DW1 0
#define F_GW1 8192
#define F_DW2 16384
#define F_GW2 32768
#define F_DW3 49152
#define F_GW3 57344
#define F_RO1 188416
#define F_RO2 196608
#define U16_END 200704
#define FW_EMB 0
#define FW_W0D 4096
#define FW_W0G 4224

// ---- LDS map: u16 plane offsets (16-row layout kept; rows 8-15 zeroed) ----
#define ZHI   0        // [16][72]
#define ZLO   1152
#define H1HI  2304     // [2][16][136]
#define H1LO  6656
#define H2HI  11008
#define H2LO  15360
#define YBHI  19712    // [16][72]
#define YBLO  20864
#define HROHI 22016    // [16][136]
#define HROLO 24192
// ---- f32 offsets ----
#define FUP   13184    // [2][16][68]
#define FVP   15360
#define FF1   17536    // [16][68]
#define FDW   18624    // [16][16][2]  (dwi, dwn) pairs
#define FW0D  19168
#define FW0G  19296
#define FB1D  19424
#define FB1G  19552
#define FB2D  19680
#define FB2G  19808
#define FB3D  19936    // [64]
#define FRB1  20000    // [128]
#define FRB2  20128    // [32]
#define FTS   20160    // [128]
#define LDS_FLOATS 20288   // 81152 bytes -> 2 blocks/CU

__device__ __forceinline__ float lipswish(float x) {
  return 0.909f * x / (1.0f + expf(-x));
}
__device__ __forceinline__ u32 bf16r(float x) {
  u32 u = __float_as_uint(x);
  return ((u + 0x7fffu + ((u >> 16) & 1u)) >> 16) & 0xffffu;
}
__device__ __forceinline__ void splitw(float x, u16& h, u16& l) {
  const u32 hb = bf16r(x);
  h = (u16)hb;
  l = (u16)bf16r(x - __uint_as_float(hb << 16));
}

// ---------------- prep: weight-norm + bf16 fragment pack (verbatim r12, verified) ----------------
__global__ void prep_kernel(const float* dr_v1, const float* dr_g1,
                            const float* dr_v2, const float* dr_g2,
                            const float* dr_v3, const float* dr_g3,
                            const float* di_v1, const float* di_g1,
                            const float* di_v2, const float* di_g2,
                            const float* di_v3, const float* di_g3,
                            const float* emb_W, const float* ro_W1, const float* ro_W2,
                            float* ws) {
  __shared__ float sred[2];
  u16* wsu = (u16*)ws;
  float* wsf = (float*)(wsu + U16_END);
  const int mat = blockIdx.y;
  const int row = blockIdx.x;
  const int i = threadIdx.x;
  const float* v = nullptr; const float* g = nullptr;
  int rows = 0, len = 0, O = 0; long F = -1; int l1 = 0; int w0 = 0;
  switch (mat) {
    case 0: v = dr_v1; g = dr_g1; rows = 128;  len = 65;  O = 128;  F = F_DW1; l1 = 1; w0 = FW_W0D; break;
    case 1: v = dr_v2; g = dr_g2; rows = 128;  len = 128; O = 128;  F = F_DW2; break;
    case 2: v = dr_v3; g = dr_g3; rows = 64;   len = 128; O = 64;   F = F_DW3; break;
    case 3: v = di_v1; g = di_g1; rows = 128;  len = 65;  O = 128;  F = F_GW1; l1 = 1; w0 = FW_W0G; break;
    case 4: v = di_v2; g = di_g2; rows = 128;  len = 128; O = 128;  F = F_GW2; break;
    case 5: v = di_v3; g = di_g3; rows = 1024; len = 128; O = 1024; F = F_GW3; break;
    case 6: v = emb_W; g = nullptr; rows = 64;  len = 64;  break;
    case 7: v = ro_W1; g = nullptr; rows = 128; len = 64;  O = 128; F = F_RO1; break;
    case 8: v = ro_W2; g = nullptr; rows = 32;  len = 128; O = 32;  F = F_RO2; break;
  }
  if (row >= rows) return;
  const float x = (i < len) ? v[(size_t)row * len + i] : 0.0f;
  float scale = 1.0f;
  if (g != nullptr) {
    float ss = x * x;
    #pragma unroll
    for (int d = 1; d < 64; d <<= 1) ss += __shfl_xor(ss, d);
    if ((i & 63) == 0) sred[i >> 6] = ss;
    __syncthreads();
    scale = g[row] / sqrtf(sred[0] + sred[1]);
  }
  const float xs = x * scale;
  if (mat == 6) {
    if (i < len) wsf[FW_EMB + i * 64 + row] = xs;
    return;
  }
  int ro = row;
  if (mat == 5) ro = ((row & 15) << 6) | (row >> 4);   // col permute: n*64 + l
  if (l1) {
    if (i == 0) wsf[w0 + row] = xs;
    if (i >= 1 && i < len) {
      const int kk = i - 1;
      wsu[F + ((size_t)((kk >> 3) * O + ro)) * 8 + (kk & 7)] = (u16)bf16r(xs);
    }
  } else if (i < len) {
    wsu[F + ((size_t)((i >> 3) * O + ro)) * 8 + (i & 7)] = (u16)bf16r(xs);
  }
}

__device__ __forceinline__ f32x4 mfma2(bf16x8 hi, bf16x8 lo, bf16x8 b, f32x4 acc) {
  acc = __builtin_amdgcn_mfma_f32_16x16x32_bf16(hi, b, acc, 0, 0, 0);
  acc = __builtin_amdgcn_mfma_f32_16x16x32_bf16(lo, b, acc, 0, 0, 0);
  return acc;
}
__device__ __forceinline__ bf16x8 ldfrag(const u16* p) { return *(const bf16x8*)p; }

// ---------------- main persistent kernel: 128 blocks x 512 threads, 8 rows/block ----------------
__global__ void __launch_bounds__(512)
sde_main(const float* __restrict__ init_noise, const float* __restrict__ bm,
         const float* __restrict__ ts_g, const int* __restrict__ p_steps,
         const int* __restrict__ p_mult, const float* __restrict__ emb_b,
         const float* __restrict__ dr_b1, const float* __restrict__ dr_b2, const float* __restrict__ dr_b3,
         const float* __restrict__ di_b1, const float* __restrict__ di_b2, const float* __restrict__ di_b3,
         const float* __restrict__ ro_b1, const float* __restrict__ ro_b2,
         const float* __restrict__ ws, float* __restrict__ out)
{
  __shared__ __align__(16) float sm[LDS_FLOATS];   // 81152 B -> 2 blocks/CU
  u16* lu = (u16*)sm;

  const int t = threadIdx.x;
  const int b0 = blockIdx.x * NB;
  const u16* __restrict__ wsu = (const u16*)ws;
  const float* __restrict__ wsf = (const float*)(wsu + U16_END);
  const int steps = p_steps[0], mult = p_mult[0];

  // ---- stage constants ----
  {
    if (t < 128) { sm[FTS + t] = ts_g[t]; sm[FW0D + t] = wsf[FW_W0D + t]; sm[FW0G + t] = wsf[FW_W0G + t]; }
    else if (t < 256) { const int i = t - 128; sm[FB1D + i] = dr_b1[i]; sm[FB1G + i] = di_b1[i]; }
    else if (t < 384) { const int i = t - 256; sm[FB2D + i] = dr_b2[i]; sm[FB2G + i] = di_b2[i]; }
    else { const int i = t - 384; sm[FRB1 + i] = ro_b1[i];
           if (i < 64) sm[FB3D + i] = dr_b3[i];
           else if (i < 96) sm[FRB2 + i - 64] = ro_b2[i - 64]; }
    if (t < 256) { float2 zz; zz.x = 0.f; zz.y = 0.f;      // zeroes ALL 16 FDW rows; rows 8-15 stay 0
                   *(float2*)&sm[FDW + (t >> 4) * 32 + (t & 15) * 2] = zz; }
  }

  // ---- init: y0 for rows < NB; rows 8-15 zeroed ----
  const int r_own = t >> 5;
  const int o_own = (t & 31) * 2;
  float yA = 0.f, yB = 0.f, zA = 0.f, zB = 0.f, fA = 0.f, fB = 0.f, vA = 0.f, vB = 0.f;
  {
    float a0 = 0.f, a1 = 0.f;
    if (r_own < NB) {
      const float* __restrict__ inr = init_noise + (size_t)(b0 + r_own) * 64;
      a0 = emb_b[o_own]; a1 = emb_b[o_own + 1];
      #pragma unroll 8
      for (int i = 0; i < 64; ++i) {
        const float x = inr[i];
        a0 = fmaf(x, wsf[FW_EMB + i * 64 + o_own], a0);
        a1 = fmaf(x, wsf[FW_EMB + i * 64 + o_own + 1], a1);
      }
    }
    yA = a0; zA = a0; yB = a1; zB = a1;
    u16 h0, l0, h1, l1;
    splitw(a0, h0, l0); splitw(a1, h1, l1);
    const u32 hw = (u32)h0 | ((u32)h1 << 16);
    const u32 lw = (u32)l0 | ((u32)l1 << 16);
    *(u32*)(lu + ZHI + r_own * 72 + o_own) = hw;
    *(u32*)(lu + ZLO + r_own * 72 + o_own) = lw;
    *(u32*)(lu + YBHI + r_own * 72 + o_own) = hw;
    *(u32*)(lu + YBLO + r_own * 72 + o_own) = lw;
  }

  const int w = t >> 6;          // wave 0..7
  const int lane = t & 63;
  const int g = lane >> 4;       // k-octet group
  const int c = lane & 15;       // A-row / col index
  const int net = w >> 2;        // waves 0-3 drift, 4-7 diffusion
  const int nt0 = (w & 3) * 2;   // two N-tiles per wave (L1/L2)
  const int lt = w & 3;          // gW3 latent tile
  const int nh = w >> 2;         // gW3 noise half

  // ---- small per-wave weight fragments (72 VGPRs total; NO gW3 residency, NO pins) ----
  bf16x8 rw1[2][2], rw2[2][4];
  #pragma unroll
  for (int ti = 0; ti < 2; ++ti) {
    const int col = (nt0 + ti) * 16 + c;
    #pragma unroll
    for (int kt = 0; kt < 2; ++kt)
      rw1[ti][kt] = ldfrag(wsu + (net ? F_GW1 : F_DW1) + ((size_t)((kt * 4 + g) * 128 + col)) * 8);
    #pragma unroll
    for (int kt = 0; kt < 4; ++kt)
      rw2[ti][kt] = ldfrag(wsu + (net ? F_GW2 : F_DW2) + ((size_t)((kt * 4 + g) * 128 + col)) * 8);
  }
  bf16x8 rro1[2];
  #pragma unroll
  for (int kt = 0; kt < 2; ++kt)
    rro1[kt] = ldfrag(wsu + F_RO1 + ((size_t)((kt * 4 + g) * 128 + w * 16 + c)) * 8);
  bf16x8 rx4[4];                 // dW3 tile (waves 0-3) or ro2 tile (waves 6-7)
  {
    const long base = (w < 4) ? (long)F_DW3 : (long)F_RO2;
    const int O3 = (w < 4) ? 64 : 32;
    const int col3 = ((w < 4) ? w : ((w >= 6) ? (w - 6) : 0)) * 16 + c;
    #pragma unroll
    for (int kt = 0; kt < 4; ++kt)
      rx4[kt] = ldfrag(wsu + base + ((size_t)((kt * 4 + g) * O3 + col3)) * 8);
  }
  // gW3 bias for this wave's (nh, lt) block -> registers
  float cb3[8];
  #pragma unroll
  for (int a = 0; a < 8; ++a)
    cb3[a] = di_b3[(lt * 16 + c) * 16 + (nh * 8 + a)];

  __syncthreads();

  #pragma unroll 1
  for (int k = 0; k < TT; ++k) {
    const float tval = sm[FTS + k];

    // ==== P1: L1 both nets + ro1(y[k-1]) + noise rotation (rows<8 only) ====
    {
      bf16x8 zh[2], zl[2];
      #pragma unroll
      for (int kt = 0; kt < 2; ++kt) {
        zh[kt] = ldfrag(lu + ZHI + c * 72 + kt * 32 + g * 8);
        zl[kt] = ldfrag(lu + ZLO + c * 72 + kt * 32 + g * 8);
      }
      #pragma unroll
      for (int ti = 0; ti < 2; ++ti) {
        const int col = (nt0 + ti) * 16 + c;
        const float ci = net ? fmaf(tval, sm[FW0G + col], sm[FB1G + col])
                             : fmaf(tval, sm[FW0D + col], sm[FB1D + col]);
        f32x4 acc = {ci, ci, ci, ci};
        #pragma unroll
        for (int kt = 0; kt < 2; ++kt) acc = mfma2(zh[kt], zl[kt], rw1[ti][kt], acc);
        #pragma unroll
        for (int j = 0; j < 4; ++j) {
          u16 hh, ll; splitw(lipswish(acc[j]), hh, ll);
          lu[H1HI + net * 2176 + (g * 4 + j) * 136 + col] = hh;
          lu[H1LO + net * 2176 + (g * 4 + j) * 136 + col] = ll;
        }
      }
      if (k > 0) {           // readout stage 1 for token k-1
        bf16x8 yh[2], yl[2];
        #pragma unroll
        for (int kt = 0; kt < 2; ++kt) {
          yh[kt] = ldfrag(lu + YBHI + c * 72 + kt * 32 + g * 8);
          yl[kt] = ldfrag(lu + YBLO + c * 72 + kt * 32 + g * 8);
        }
        const int col = w * 16 + c;
        const float ci = sm[FRB1 + col];
        f32x4 acc = {ci, ci, ci, ci};
        #pragma unroll
        for (int kt = 0; kt < 2; ++kt) acc = mfma2(yh[kt], yl[kt], rro1[kt], acc);
        #pragma unroll
        for (int j = 0; j < 4; ++j) {
          u16 hh, ll; splitw(lipswish(acc[j]), hh, ll);
          lu[HROHI + (g * 4 + j) * 136 + col] = hh;
          lu[HROLO + (g * 4 + j) * 136 + col] = ll;
        }
      }
      if (t >= 256 && t < 384) {   // rotate noise for rows 0-7 only
        const int i2 = t - 256, rr = i2 >> 4, nn = i2 & 15;
        const float old = sm[FDW + rr * 32 + nn * 2 + 1];
        float nv = 0.f;
        if (k < TT - 1)
          nv = bm[((size_t)k * NBATCH + b0 + rr) * 16 + nn] * sqrtf(sm[FTS + k + 1] - tval);
        float2 wv; wv.x = old; wv.y = nv;
        *(float2*)&sm[FDW + rr * 32 + nn * 2] = wv;
      }
    }
    __syncthreads();

    // ==== P2: L2 both nets + ro2 -> out token k-1 ====
    {
      bf16x8 ah[4], al[4];
      #pragma unroll
      for (int kt = 0; kt < 4; ++kt) {
        ah[kt] = ldfrag(lu + H1HI + net * 2176 + c * 136 + kt * 32 + g * 8);
        al[kt] = ldfrag(lu + H1LO + net * 2176 + c * 136 + kt * 32 + g * 8);
      }
      #pragma unroll
      for (int ti = 0; ti < 2; ++ti) {
        const int col = (nt0 + ti) * 16 + c;
        const float ci = net ? sm[FB2G + col] : sm[FB2D + col];
        f32x4 acc = {ci, ci, ci, ci};
        #pragma unroll
        for (int kt = 0; kt < 4; ++kt) acc = mfma2(ah[kt], al[kt], rw2[ti][kt], acc);
        #pragma unroll
        for (int j = 0; j < 4; ++j) {
          u16 hh, ll; splitw(lipswish(acc[j]), hh, ll);
          lu[H2HI + net * 2176 + (g * 4 + j) * 136 + col] = hh;
          lu[H2LO + net * 2176 + (g * 4 + j) * 136 + col] = ll;
        }
      }
      if (k > 0 && w >= 6) { // readout stage 2, token k-1 (rows<8 stores)
        bf16x8 hh[4], hl[4];
        #pragma unroll
        for (int kt = 0; kt < 4; ++kt) {
          hh[kt] = ldfrag(lu + HROHI + c * 136 + kt * 32 + g * 8);
          hl[kt] = ldfrag(lu + HROLO + c * 136 + kt * 32 + g * 8);
        }
        const int col = (w - 6) * 16 + c;
        const float ci = sm[FRB2 + col];
        f32x4 acc = {ci, ci, ci, ci};
        #pragma unroll
        for (int kt = 0; kt < 4; ++kt) acc = mfma2(hh[kt], hl[kt], rx4[kt], acc);
        const int tg = k - 1;
        const int matched = (mult > 0 && (tg % mult) == 0) ? (tg / mult) : -1;
        if (g < 2) {
          #pragma unroll
          for (int j = 0; j < 4; ++j) {
            const int m = g * 4 + j;
            out[((size_t)(b0 + m) * TT + tg) * OUTD + col] = acc[j];
            if (matched >= 0 && matched < steps)
              out[(size_t)NBATCH * TT * OUTD + ((size_t)(b0 + m) * steps + matched) * OUTD + col] = acc[j];
          }
        }
      }
    }
    __syncthreads();

    // ==== P3: dW3 (waves 0-3) + gW3 STREAMED with batched loads + in-flight contraction ====
    {
      if (w < 4) {
        bf16x8 dh[4], dl[4];
        #pragma unroll
        for (int kt = 0; kt < 4; ++kt) {
          dh[kt] = ldfrag(lu + H2HI + c * 136 + kt * 32 + g * 8);
          dl[kt] = ldfrag(lu + H2LO + c * 136 + kt * 32 + g * 8);
        }
        const int col = w * 16 + c;
        const float ci = sm[FB3D + col];
        f32x4 acc = {ci, ci, ci, ci};
        #pragma unroll
        for (int kt = 0; kt < 4; ++kt) acc = mfma2(dh[kt], dl[kt], rx4[kt], acc);
        #pragma unroll
        for (int j = 0; j < 4; ++j) sm[FF1 + (g * 4 + j) * 68 + col] = acc[j];
      }
      bf16x8 gh[4], gl[4];
      #pragma unroll
      for (int kt = 0; kt < 4; ++kt) {
        gh[kt] = ldfrag(lu + H2HI + 2176 + c * 136 + kt * 32 + g * 8);
        gl[kt] = ldfrag(lu + H2LO + 2176 + c * 136 + kt * 32 + g * 8);
      }
      float ua[4] = {0.f, 0.f, 0.f, 0.f}, va[4] = {0.f, 0.f, 0.f, 0.f};
      #pragma unroll
      for (int half = 0; half < 2; ++half) {
        // batch-issue 16 B-fragment loads (4 tiles x 4 k-frags) before the MFMAs
        bf16x8 bfr[4][4];
        #pragma unroll
        for (int a4 = 0; a4 < 4; ++a4) {
          const int n = nh * 8 + half * 4 + a4;
          const int colb = n * 64 + lt * 16 + c;
          #pragma unroll
          for (int kt = 0; kt < 4; ++kt)
            bfr[a4][kt] = ldfrag(wsu + F_GW3 + ((size_t)((kt * 4 + g) * 1024 + colb)) * 8);
        }
        f32x4 acc0 = {cb3[half*4+0], cb3[half*4+0], cb3[half*4+0], cb3[half*4+0]};
        f32x4 acc1 = {cb3[half*4+1], cb3[half*4+1], cb3[half*4+1], cb3[half*4+1]};
        f32x4 acc2 = {cb3[half*4+2], cb3[half*4+2], cb3[half*4+2], cb3[half*4+2]};
        f32x4 acc3 = {cb3[half*4+3], cb3[half*4+3], cb3[half*4+3], cb3[half*4+3]};
        #pragma unroll
        for (int kt = 0; kt < 4; ++kt) {   // 4 independent chains interleaved
          acc0 = __builtin_amdgcn_mfma_f32_16x16x32_bf16(gh[kt], bfr[0][kt], acc0, 0, 0, 0);
          acc1 = __builtin_amdgcn_mfma_f32_16x16x32_bf16(gh[kt], bfr[1][kt], acc1, 0, 0, 0);
          acc2 = __builtin_amdgcn_mfma_f32_16x16x32_bf16(gh[kt], bfr[2][kt], acc2, 0, 0, 0);
          acc3 = __builtin_amdgcn_mfma_f32_16x16x32_bf16(gh[kt], bfr[3][kt], acc3, 0, 0, 0);
          acc0 = __builtin_amdgcn_mfma_f32_16x16x32_bf16(gl[kt], bfr[0][kt], acc0, 0, 0, 0);
          acc1 = __builtin_amdgcn_mfma_f32_16x16x32_bf16(gl[kt], bfr[1][kt], acc1, 0, 0, 0);
          acc2 = __builtin_amdgcn_mfma_f32_16x16x32_bf16(gl[kt], bfr[2][kt], acc2, 0, 0, 0);
          acc3 = __builtin_amdgcn_mfma_f32_16x16x32_bf16(gl[kt], bfr[3][kt], acc3, 0, 0, 0);
        }
        #pragma unroll
        for (int j = 0; j < 4; ++j) {
          const int nb = nh * 8 + half * 4;
          const float2 dw0 = *(const float2*)&sm[FDW + (g * 4 + j) * 32 + (nb + 0) * 2];
          const float2 dw1 = *(const float2*)&sm[FDW + (g * 4 + j) * 32 + (nb + 1) * 2];
          const float2 dw2 = *(const float2*)&sm[FDW + (g * 4 + j) * 32 + (nb + 2) * 2];
          const float2 dw3 = *(const float2*)&sm[FDW + (g * 4 + j) * 32 + (nb + 3) * 2];
          ua[j] = fmaf(acc0[j], dw0.x, fmaf(acc1[j], dw1.x, fmaf(acc2[j], dw2.x, fmaf(acc3[j], dw3.x, ua[j]))));
          va[j] = fmaf(acc0[j], dw0.y, fmaf(acc1[j], dw1.y, fmaf(acc2[j], dw2.y, fmaf(acc3[j], dw3.y, va[j]))));
        }
      }
      #pragma unroll
      for (int j = 0; j < 4; ++j) {
        sm[FUP + nh * 1088 + (g * 4 + j) * 68 + lt * 16 + c] = ua[j];
        sm[FVP + nh * 1088 + (g * 4 + j) * 68 + lt * 16 + c] = va[j];
      }
    }
    __syncthreads();

    // ==== P4: Heun update (owner regs) + state planes ====
    {
      const float2 f1v = *(const float2*)&sm[FF1 + r_own * 68 + o_own];
      const float2 u0 = *(const float2*)&sm[FUP + r_own * 68 + o_own];
      const float2 u1p = *(const float2*)&sm[FUP + 1088 + r_own * 68 + o_own];
      const float2 v0 = *(const float2*)&sm[FVP + r_own * 68 + o_own];
      const float2 v1p = *(const float2*)&sm[FVP + 1088 + r_own * 68 + o_own];
      const float u1A = u0.x + u1p.x, u1B = u0.y + u1p.y;
      const float v1A = v0.x + v1p.x, v1B = v0.y + v1p.y;
      const float dti = (k > 0) ? (tval - sm[FTS + k - 1]) : 0.f;
      const float dtn = (k < TT - 1) ? (sm[FTS + k + 1] - tval) : 0.f;
      yA += 0.5f * (fA + f1v.x) * dti + 0.5f * (vA + u1A);
      yB += 0.5f * (fB + f1v.y) * dti + 0.5f * (vB + u1B);
      zA = 2.f * yA - zA + f1v.x * dtn + v1A;
      zB = 2.f * yB - zB + f1v.y * dtn + v1B;
      fA = f1v.x; fB = f1v.y; vA = v1A; vB = v1B;
      u16 h0, l0, h1, l1;
      splitw(zA, h0, l0); splitw(zB, h1, l1);
      *(u32*)(lu + ZHI + r_own * 72 + o_own) = (u32)h0 | ((u32)h1 << 16);
      *(u32*)(lu + ZLO + r_own * 72 + o_own) = (u32)l0 | ((u32)l1 << 16);
      splitw(yA, h0, l0); splitw(yB, h1, l1);
      *(u32*)(lu + YBHI + r_own * 72 + o_own) = (u32)h0 | ((u32)h1 << 16);
      *(u32*)(lu + YBLO + r_own * 72 + o_own) = (u32)l0 | ((u32)l1 << 16);
    }
    __syncthreads();
  }

  // ==== tail: readout of token TT-1 ====
  {
    bf16x8 yh[2], yl[2];
    #pragma unroll
    for (int kt = 0; kt < 2; ++kt) {
      yh[kt] = ldfrag(lu + YBHI + c * 72 + kt * 32 + g * 8);
      yl[kt] = ldfrag(lu + YBLO + c * 72 + kt * 32 + g * 8);
    }
    const int col = w * 16 + c;
    const float ci = sm[FRB1 + col];
    f32x4 acc = {ci, ci, ci, ci};
    #pragma unroll
    for (int kt = 0; kt < 2; ++kt) acc = mfma2(yh[kt], yl[kt], rro1[kt], acc);
    #pragma unroll
    for (int j = 0; j < 4; ++j) {
      u16 hh, ll; splitw(lipswish(acc[j]), hh, ll);
      lu[HROHI + (g * 4 + j) * 136 + col] = hh;
      lu[HROLO + (g * 4 + j) * 136 + col] = ll;
    }
  }
  __syncthreads();
  if (w >= 6) {
    bf16x8 hh[4], hl[4];
    #pragma unroll
    for (int kt = 0; kt < 4; ++kt) {
      hh[kt] = ldfrag(lu + HROHI + c * 136 + kt * 32 + g * 8);
      hl[kt] = ldfrag(lu + HROLO + c * 136 + kt * 32 + g * 8);
    }
    const int col = (w - 6) * 16 + c;
    const float ci = sm[FRB2 + col];
    f32x4 acc = {ci, ci, ci, ci};
    #pragma unroll
    for (int kt = 0; kt < 4; ++kt) acc = mfma2(hh[kt], hl[kt], rx4[kt], acc);
    const int tg = TT - 1;
    const int matched = (mult > 0 && (tg % mult) == 0) ? (tg / mult) : -1;
    if (g < 2) {
      #pragma unroll
      for (int j = 0; j < 4; ++j) {
        const int m = g * 4 + j;
        out[((size_t)(b0 + m) * TT + tg) * OUTD + col] = acc[j];
        if (matched >= 0 && matched < steps)
          out[(size_t)NBATCH * TT * OUTD + ((size_t)(b0 + m) * steps + matched) * OUTD + col] = acc[j];
      }
    }
  }
}

extern "C" void kernel_launch(void* const* d_in, const int* in_sizes, int n_in,
                              void* d_out, int out_size, void* d_ws, size_t ws_size,
                              hipStream_t stream) {
  (void)in_sizes; (void)n_in; (void)out_size; (void)ws_size;
  const float* init_noise = (const float*)d_in[0];
  const float* bm_noise   = (const float*)d_in[1];
  const float* ts         = (const float*)d_in[2];
  const int*   p_steps    = (const int*)d_in[3];
  const int*   p_mult     = (const int*)d_in[4];
  const float* emb_W = (const float*)d_in[5];
  const float* emb_b = (const float*)d_in[6];
  const float* dr_v1 = (const float*)d_in[7];
  const float* dr_g1 = (const float*)d_in[8];
  const float* dr_b1 = (const float*)d_in[9];
  const float* dr_v2 = (const float*)d_in[10];
  const float* dr_g2 = (const float*)d_in[11];
  const float* dr_b2 = (const float*)d_in[12];
  const float* dr_v3 = (const float*)d_in[13];
  const float* dr_g3 = (const float*)d_in[14];
  const float* dr_b3 = (const float*)d_in[15];
  const float* di_v1 = (const float*)d_in[16];
  const float* di_g1 = (const float*)d_in[17];
  const float* di_b1 = (const float*)d_in[18];
  const float* di_v2 = (const float*)d_in[19];
  const float* di_g2 = (const float*)d_in[20];
  const float* di_b2 = (const float*)d_in[21];
  const float* di_v3 = (const float*)d_in[22];
  const float* di_g3 = (const float*)d_in[23];
  const float* di_b3 = (const float*)d_in[24];
  const float* ro_W1 = (const float*)d_in[25];
  const float* ro_b1 = (const float*)d_in[26];
  const float* ro_W2 = (const float*)d_in[27];
  const float* ro_b2 = (const float*)d_in[28];
  float* ws = (float*)d_ws;
  float* out = (float*)d_out;

  prep_kernel<<<dim3(1024, 9), 128, 0, stream>>>(
      dr_v1, dr_g1, dr_v2, dr_g2, dr_v3, dr_g3,
      di_v1, di_g1, di_v2, di_g2, di_v3, di_g3,
      emb_W, ro_W1, ro_W2, ws);

  sde_main<<<NBLK, 512, 0, stream>>>(
      init_noise, bm_noise, ts, p_steps, p_mult,
      emb_b, dr_b1, dr_b2, dr_b3, di_b1, di_b2, di_b3,
      ro_b1, ro_b2, ws, out);
}